// Round 7
// baseline (98.447 us; speedup 1.0000x reference)
//
#include <hip/hip_runtime.h>
#include <math.h>

#define NB 8192
#define ND 128
#define GSTEP 64          // j rows staged per step
#define NSTEP 4           // steps per block -> 256 j per block
#define NJB 32            // j-groups (8192 / 256)

// (log2 e)^2 folded into the squared-norm terms: sqrt(c2*sq) = d*log2e,
// v_exp_f32(-that) = exp(-d).
#define C2F 2.0813689810056077f
#define NC2 (-4.1627379620112154f)   // -2*c2, fma coefficient on dot

typedef __bf16 bf16x8 __attribute__((ext_vector_type(8)));
typedef float f32x4 __attribute__((ext_vector_type(4)));

typedef __attribute__((address_space(3))) void lds_void_t;
typedef __attribute__((address_space(1))) const void gconst_void_t;

__device__ __forceinline__ unsigned f2bf(float f) {
    union { float f; unsigned u; } v; v.f = f;
    unsigned r = v.u + 0x7FFFu + ((v.u >> 16) & 1u);  // RNE, inputs finite
    return r >> 16;
}

// prep: 2 rows per wave (32 lanes each, float4 loads). Emits bf16 copies,
// c2-scaled ||sk||^2 / ||im||^2, diag = ||sk-im|| (fp32). Zeroes gacc/ticket.
__global__ void __launch_bounds__(256) prep_kernel(
    const float* __restrict__ sk, const float* __restrict__ im,
    unsigned short* __restrict__ skb, unsigned short* __restrict__ imb,
    float* __restrict__ skn, float* __restrict__ imn,
    float* __restrict__ diag, float* __restrict__ gacc,
    unsigned* __restrict__ ticket) {
    if (blockIdx.x == 0 && threadIdx.x == 0) { *gacc = 0.f; *ticket = 0u; }
    const int wave = threadIdx.x >> 6, lane = threadIdx.x & 63;
    const int half = lane >> 5, l32 = lane & 31;
    const int row = blockIdx.x * 8 + wave * 2 + half;
    const size_t off = (size_t)row * ND + l32 * 4;
    const float4 a = *reinterpret_cast<const float4*>(sk + off);
    const float4 b = *reinterpret_cast<const float4*>(im + off);
    ushort4 pa, pb;
    pa.x = (unsigned short)f2bf(a.x); pa.y = (unsigned short)f2bf(a.y);
    pa.z = (unsigned short)f2bf(a.z); pa.w = (unsigned short)f2bf(a.w);
    pb.x = (unsigned short)f2bf(b.x); pb.y = (unsigned short)f2bf(b.y);
    pb.z = (unsigned short)f2bf(b.z); pb.w = (unsigned short)f2bf(b.w);
    *reinterpret_cast<ushort4*>(skb + off) = pa;
    *reinterpret_cast<ushort4*>(imb + off) = pb;
    float sa = a.x * a.x + a.y * a.y + a.z * a.z + a.w * a.w;
    float sb = b.x * b.x + b.y * b.y + b.z * b.z + b.w * b.w;
    float dx = a.x - b.x, dy = a.y - b.y, dz = a.z - b.z, dw = a.w - b.w;
    float sd = dx * dx + dy * dy + dz * dz + dw * dw;
#pragma unroll
    for (int st = 1; st < 32; st <<= 1) {
        sa += __shfl_xor(sa, st);
        sb += __shfl_xor(sb, st);
        sd += __shfl_xor(sd, st);
    }
    if (l32 == 0) {
        skn[row] = sa * C2F;
        imn[row] = sb * C2F;
        diag[row] = sqrtf(sd);
    }
}

// tile: block = 512 threads (8 waves), covers 512 i x 256 j.
// B (sk) fragments: loaded from global ONCE into registers (64 VGPR/wave).
// A (im): double-buffered 64-row LDS tile per step via global_load_lds with
// inverse-swizzled source; ds_read applies the same involution (^ row&15).
// Row-sums accumulate in registers across steps; one write per wave at end.
__global__ void __launch_bounds__(512, 2) tile_kernel(
    const unsigned short* __restrict__ skb, const unsigned short* __restrict__ imb,
    const float* __restrict__ skn, const float* __restrict__ imn,
    float* __restrict__ partial) {
    __shared__ unsigned short Ast[2][GSTEP * ND];   // 2 x 16 KB

    const int t = threadIdx.x;
    const int w = t >> 6, lane = t & 63;
    const int hi = lane >> 4, lo = lane & 15;
    const int iw = blockIdx.x * 512 + w * 64;       // wave's 64 i columns
    const int jg0 = blockIdx.y * (GSTEP * NSTEP);   // block's j base

    // Persistent B (sk) fragments: bfr[n][kk]; col = lo, k = kk*32 + hi*8.
    bf16x8 bfr[4][4];
#pragma unroll
    for (int n = 0; n < 4; ++n) {
        const unsigned short* bp = skb + (size_t)(iw + n * 16 + lo) * ND + hi * 8;
#pragma unroll
        for (int kk = 0; kk < 4; ++kk)
            bfr[n][kk] = *reinterpret_cast<const bf16x8*>(bp + kk * 32);
    }
    float skv[4];
#pragma unroll
    for (int n = 0; n < 4; ++n) skv[n] = skn[iw + n * 16 + lo];

    // Stage a 64-row im step-tile: wave w stages rows [w*8, w*8+8).
    // LDS[row][slot] = global[row][slot ^ (row&15)] (both-sides involution).
#define STAGE_A(buf, jrow0)                                                     \
    {                                                                           \
        _Pragma("unroll")                                                       \
        for (int q = 0; q < 2; ++q) {                                           \
            const int rl = w * 8 + q * 4 + hi;                                  \
            const int cs = lo ^ (rl & 15);                                      \
            const unsigned short* gp = imb + (size_t)((jrow0) + rl) * ND + cs * 8; \
            __builtin_amdgcn_global_load_lds((gconst_void_t*)gp,                \
                (lds_void_t*)(&Ast[(buf)][(w * 8 + q * 4) * ND]), 16, 0, 0);    \
        }                                                                       \
    }

    STAGE_A(0, jg0)
    __syncthreads();

    float sacc[4] = {0.f, 0.f, 0.f, 0.f};

#pragma unroll
    for (int s = 0; s < NSTEP; ++s) {
        const int jb = jg0 + s * GSTEP;
        if (s + 1 < NSTEP) STAGE_A((s + 1) & 1, jb + GSTEP)

        // c2-scaled im norms for this step's j rows (indexed by m, hi*4+r).
        float imnv[4][4];
#pragma unroll
        for (int m = 0; m < 4; ++m) {
            float4 v = *reinterpret_cast<const float4*>(imn + jb + m * 16 + hi * 4);
            imnv[m][0] = v.x; imnv[m][1] = v.y; imnv[m][2] = v.z; imnv[m][3] = v.w;
        }

        f32x4 acc[4][4];
#pragma unroll
        for (int m = 0; m < 4; ++m)
#pragma unroll
            for (int n = 0; n < 4; ++n)
                acc[m][n] = (f32x4){0.f, 0.f, 0.f, 0.f};

        const char* Ab = (const char*)Ast[s & 1];
#pragma unroll
        for (int kk = 0; kk < 4; ++kk) {
            const int cb = ((kk * 4 + hi) ^ lo) << 4;   // swizzled byte slot
            bf16x8 af[4];
#pragma unroll
            for (int m = 0; m < 4; ++m)
                af[m] = *reinterpret_cast<const bf16x8*>(Ab + (m * 16 + lo) * 256 + cb);
#pragma unroll
            for (int m = 0; m < 4; ++m)
#pragma unroll
                for (int n = 0; n < 4; ++n)
                    acc[m][n] = __builtin_amdgcn_mfma_f32_16x16x32_bf16(
                        af[m], bfr[n][kk], acc[m][n], 0, 0, 0);
        }

        // Epilogue: i fixed per n (col=lo); j = jb + m*16 + hi*4 + r.
#pragma unroll
        for (int n = 0; n < 4; ++n) {
            float ssum = 0.f;
#pragma unroll
            for (int m = 0; m < 4; ++m) {
#pragma unroll
                for (int r = 0; r < 4; ++r) {
                    float sq2 = fmaf(NC2, acc[m][n][r], skv[n]) + imnv[m][r];
                    sq2 = fmaxf(sq2, 0.f);
                    float d2;
                    asm("v_sqrt_f32 %0, %1" : "=v"(d2) : "v"(sq2));
                    float e;
                    asm("v_exp_f32 %0, -%1" : "=v"(e) : "v"(d2));
                    ssum += e;
                }
            }
            sacc[n] += ssum;
        }
        if (s + 1 < NSTEP) __syncthreads();
    }

    // Fold the hi groups (j-partitions) and write this wave's 64 partials.
#pragma unroll
    for (int n = 0; n < 4; ++n) {
        sacc[n] += __shfl_xor(sacc[n], 16);
        sacc[n] += __shfl_xor(sacc[n], 32);
    }
    if (lane < 16) {
#pragma unroll
        for (int n = 0; n < 4; ++n)
            partial[(size_t)blockIdx.y * NB + iw + n * 16 + lo] = sacc[n];
    }
#undef STAGE_A
}

// finalize: thread per row; 32 coalesced partial loads; log + diag; block
// reduce; device atomic + ticket, last block writes the mean.
__global__ void finalize_kernel(const float* __restrict__ partial,
                                const float* __restrict__ diag,
                                float* __restrict__ gacc, unsigned* __restrict__ ticket,
                                float* __restrict__ out) {
    const int i = blockIdx.x * 256 + threadIdx.x;
    float rs = 0.f;
#pragma unroll
    for (int c = 0; c < NJB; ++c) rs += partial[(size_t)c * NB + i];
    float v = __logf(rs) + diag[i];
    __shared__ float red[256];
    red[threadIdx.x] = v;
    __syncthreads();
    for (int st = 128; st > 0; st >>= 1) {
        if (threadIdx.x < st) red[threadIdx.x] += red[threadIdx.x + st];
        __syncthreads();
    }
    if (threadIdx.x == 0) {
        atomicAdd(gacc, red[0]);
        __threadfence();
        unsigned old = atomicAdd(ticket, 1u);
        if (old == (NB / 256) - 1) {
            float tot = atomicAdd(gacc, 0.f);   // device-coherent read
            out[0] = tot / (float)NB;
        }
    }
}

extern "C" void kernel_launch(void* const* d_in, const int* in_sizes, int n_in,
                              void* d_out, int out_size, void* d_ws, size_t ws_size,
                              hipStream_t stream) {
    const float* sk = (const float*)d_in[0];
    const float* im = (const float*)d_in[1];
    float* out = (float*)d_out;
    float* ws = (float*)d_ws;

    unsigned short* skb = (unsigned short*)ws;              // NB*ND bf16 (2 MB)
    unsigned short* imb = skb + (size_t)NB * ND;            // NB*ND bf16 (2 MB)
    float* fbase   = ws + (size_t)NB * ND;
    float* skn     = fbase;                                 // [NB] (c2-scaled)
    float* imn     = fbase + NB;                            // [NB] (c2-scaled)
    float* diag    = fbase + 2 * NB;                        // [NB]
    float* partial = fbase + 3 * NB;                        // [NJB][NB] (1 MB)
    float* gacc    = partial + (size_t)NJB * NB;            // [1]
    unsigned* ticket = (unsigned*)(gacc + 1);               // [1]

    prep_kernel<<<NB / 8, 256, 0, stream>>>(
        sk, im, skb, imb, skn, imn, diag, gacc, ticket);
    dim3 grid(NB / 512, NB / (GSTEP * NSTEP));
    tile_kernel<<<grid, 512, 0, stream>>>(skb, imb, skn, imn, partial);
    finalize_kernel<<<NB / 256, 256, 0, stream>>>(partial, diag, gacc, ticket, out);
}

// Round 8
// 90.928 us; speedup vs baseline: 1.0827x; 1.0827x over previous
//
#include <hip/hip_runtime.h>
#include <math.h>

#define NB 8192
#define ND 128
#define GSTEP 64          // j rows staged per step
#define NSTEP 8           // steps per block -> 512 j per block
#define NJB 16            // j-groups (8192 / 512)

// (log2 e)^2 folded into the squared-norm terms: sqrt(c2*sq) = d*log2e,
// v_exp_f32(-that) = exp(-d).
#define C2F 2.0813689810056077f
#define NC2 (-4.1627379620112154f)   // -2*c2, fma coefficient on dot

typedef __bf16 bf16x8 __attribute__((ext_vector_type(8)));
typedef float f32x4 __attribute__((ext_vector_type(4)));

typedef __attribute__((address_space(3))) void lds_void_t;
typedef __attribute__((address_space(1))) const void gconst_void_t;

__device__ __forceinline__ unsigned f2bf(float f) {
    union { float f; unsigned u; } v; v.f = f;
    unsigned r = v.u + 0x7FFFu + ((v.u >> 16) & 1u);  // RNE, inputs finite
    return r >> 16;
}

// prep: 2 rows per wave (32 lanes each, float4 loads). Emits bf16 copies,
// c2-scaled ||sk||^2 / ||im||^2, diag = ||sk-im|| (fp32). Zeroes gacc/ticket.
__global__ void __launch_bounds__(256) prep_kernel(
    const float* __restrict__ sk, const float* __restrict__ im,
    unsigned short* __restrict__ skb, unsigned short* __restrict__ imb,
    float* __restrict__ skn, float* __restrict__ imn,
    float* __restrict__ diag, float* __restrict__ gacc,
    unsigned* __restrict__ ticket) {
    if (blockIdx.x == 0 && threadIdx.x == 0) { *gacc = 0.f; *ticket = 0u; }
    const int wave = threadIdx.x >> 6, lane = threadIdx.x & 63;
    const int half = lane >> 5, l32 = lane & 31;
    const int row = blockIdx.x * 8 + wave * 2 + half;
    const size_t off = (size_t)row * ND + l32 * 4;
    const float4 a = *reinterpret_cast<const float4*>(sk + off);
    const float4 b = *reinterpret_cast<const float4*>(im + off);
    ushort4 pa, pb;
    pa.x = (unsigned short)f2bf(a.x); pa.y = (unsigned short)f2bf(a.y);
    pa.z = (unsigned short)f2bf(a.z); pa.w = (unsigned short)f2bf(a.w);
    pb.x = (unsigned short)f2bf(b.x); pb.y = (unsigned short)f2bf(b.y);
    pb.z = (unsigned short)f2bf(b.z); pb.w = (unsigned short)f2bf(b.w);
    *reinterpret_cast<ushort4*>(skb + off) = pa;
    *reinterpret_cast<ushort4*>(imb + off) = pb;
    float sa = a.x * a.x + a.y * a.y + a.z * a.z + a.w * a.w;
    float sb = b.x * b.x + b.y * b.y + b.z * b.z + b.w * b.w;
    float dx = a.x - b.x, dy = a.y - b.y, dz = a.z - b.z, dw = a.w - b.w;
    float sd = dx * dx + dy * dy + dz * dz + dw * dw;
#pragma unroll
    for (int st = 1; st < 32; st <<= 1) {
        sa += __shfl_xor(sa, st);
        sb += __shfl_xor(sb, st);
        sd += __shfl_xor(sd, st);
    }
    if (l32 == 0) {
        skn[row] = sa * C2F;
        imn[row] = sb * C2F;
        diag[row] = sqrtf(sd);
    }
}

// tile: block = 256 threads (4 waves), covers 128 i; each wave 64j x 32i.
// Registers: bfr[2][4]=32 + acc[4][2]=32 + af[4]=16 + imnv=16 + misc -> <=128
// => 4 waves/SIMD. LDS: 2 x 16 KB A double-buffer => 4 blocks/CU.
// B (sk) fragments loaded from global ONCE per block into registers.
// A (im) staged per step via global_load_lds, inverse-swizzled source,
// ds_read applies the matching involution (^ row&15) -> ~2 lanes/bank.
// One barrier per step; stage(s+1) issued before compute(s).
__global__ void __launch_bounds__(256, 4) tile_kernel(
    const unsigned short* __restrict__ skb, const unsigned short* __restrict__ imb,
    const float* __restrict__ skn, const float* __restrict__ imn,
    float* __restrict__ partial) {
    __shared__ unsigned short Ast[2][GSTEP * ND];   // 2 x 16 KB

    const int t = threadIdx.x;
    const int w = t >> 6, lane = t & 63;            // w in 0..3
    const int hi = lane >> 4, lo = lane & 15;
    const int iw = blockIdx.x * 128 + w * 32;       // wave's 32 i columns
    const int jg0 = blockIdx.y * (GSTEP * NSTEP);   // block's j base

    // Persistent B (sk) fragments: bfr[n][kk]; col = lo, k = kk*32 + hi*8.
    bf16x8 bfr[2][4];
#pragma unroll
    for (int n = 0; n < 2; ++n) {
        const unsigned short* bp = skb + (size_t)(iw + n * 16 + lo) * ND + hi * 8;
#pragma unroll
        for (int kk = 0; kk < 4; ++kk)
            bfr[n][kk] = *reinterpret_cast<const bf16x8*>(bp + kk * 32);
    }
    float skv[2];
#pragma unroll
    for (int n = 0; n < 2; ++n) skv[n] = skn[iw + n * 16 + lo];

    // Stage a 64-row im step-tile. Wave w stages rows [w*16, w*16+16).
    // LDS[row][slot] = global[row][slot ^ (row&15)] (both-sides involution).
#define STAGE_A(buf, jrow0)                                                       \
    {                                                                             \
        _Pragma("unroll")                                                         \
        for (int q = 0; q < 4; ++q) {                                             \
            const int rl = w * 16 + q * 4 + hi;                                   \
            const int cs = lo ^ (rl & 15);                                        \
            const unsigned short* gp = imb + (size_t)((jrow0) + rl) * ND + cs * 8;\
            __builtin_amdgcn_global_load_lds((gconst_void_t*)gp,                  \
                (lds_void_t*)(&Ast[(buf)][(w * 16 + q * 4) * ND]), 16, 0, 0);     \
        }                                                                         \
    }

    STAGE_A(0, jg0)
    __syncthreads();

    float sacc[2] = {0.f, 0.f};

    for (int s = 0; s < NSTEP; ++s) {
        const int jb = jg0 + s * GSTEP;
        if (s + 1 < NSTEP) STAGE_A((s + 1) & 1, jb + GSTEP)

        // c2-scaled im norms for this step's j rows (j = jb + m*16 + hi*4 + r).
        float imnv[4][4];
#pragma unroll
        for (int m = 0; m < 4; ++m) {
            float4 v = *reinterpret_cast<const float4*>(imn + jb + m * 16 + hi * 4);
            imnv[m][0] = v.x; imnv[m][1] = v.y; imnv[m][2] = v.z; imnv[m][3] = v.w;
        }

        f32x4 acc[4][2];
#pragma unroll
        for (int m = 0; m < 4; ++m)
#pragma unroll
            for (int n = 0; n < 2; ++n)
                acc[m][n] = (f32x4){0.f, 0.f, 0.f, 0.f};

        const char* Ab = (const char*)Ast[s & 1];
#pragma unroll
        for (int kk = 0; kk < 4; ++kk) {
            const int cb = ((kk * 4 + hi) ^ lo) << 4;   // swizzled byte slot
            bf16x8 af[4];
#pragma unroll
            for (int m = 0; m < 4; ++m)
                af[m] = *reinterpret_cast<const bf16x8*>(Ab + (m * 16 + lo) * 256 + cb);
#pragma unroll
            for (int m = 0; m < 4; ++m)
#pragma unroll
                for (int n = 0; n < 2; ++n)
                    acc[m][n] = __builtin_amdgcn_mfma_f32_16x16x32_bf16(
                        af[m], bfr[n][kk], acc[m][n], 0, 0, 0);
        }

        // Epilogue: i fixed per n (col=lo); j = jb + m*16 + hi*4 + r.
#pragma unroll
        for (int n = 0; n < 2; ++n) {
            float ssum = 0.f;
#pragma unroll
            for (int m = 0; m < 4; ++m) {
#pragma unroll
                for (int r = 0; r < 4; ++r) {
                    float sq2 = fmaf(NC2, acc[m][n][r], skv[n]) + imnv[m][r];
                    sq2 = fmaxf(sq2, 0.f);
                    float d2;
                    asm("v_sqrt_f32 %0, %1" : "=v"(d2) : "v"(sq2));
                    float e;
                    asm("v_exp_f32 %0, -%1" : "=v"(e) : "v"(d2));
                    ssum += e;
                }
            }
            sacc[n] += ssum;
        }
        __syncthreads();   // drains this step's prefetch vmcnt; buffer swap safe
    }

    // Fold the hi groups (j-partitions) and write this wave's 32 partials.
#pragma unroll
    for (int n = 0; n < 2; ++n) {
        sacc[n] += __shfl_xor(sacc[n], 16);
        sacc[n] += __shfl_xor(sacc[n], 32);
    }
    if (lane < 16) {
        partial[(size_t)blockIdx.y * NB + iw + lo] = sacc[0];
        partial[(size_t)blockIdx.y * NB + iw + 16 + lo] = sacc[1];
    }
#undef STAGE_A
}

// finalize: thread per row; 16 coalesced partial loads; log + diag; block
// reduce; device atomic + ticket, last block writes the mean.
__global__ void finalize_kernel(const float* __restrict__ partial,
                                const float* __restrict__ diag,
                                float* __restrict__ gacc, unsigned* __restrict__ ticket,
                                float* __restrict__ out) {
    const int i = blockIdx.x * 256 + threadIdx.x;
    float rs = 0.f;
#pragma unroll
    for (int c = 0; c < NJB; ++c) rs += partial[(size_t)c * NB + i];
    float v = __logf(rs) + diag[i];
    __shared__ float red[256];
    red[threadIdx.x] = v;
    __syncthreads();
    for (int st = 128; st > 0; st >>= 1) {
        if (threadIdx.x < st) red[threadIdx.x] += red[threadIdx.x + st];
        __syncthreads();
    }
    if (threadIdx.x == 0) {
        atomicAdd(gacc, red[0]);
        __threadfence();
        unsigned old = atomicAdd(ticket, 1u);
        if (old == (NB / 256) - 1) {
            float tot = atomicAdd(gacc, 0.f);   // device-coherent read
            out[0] = tot / (float)NB;
        }
    }
}

extern "C" void kernel_launch(void* const* d_in, const int* in_sizes, int n_in,
                              void* d_out, int out_size, void* d_ws, size_t ws_size,
                              hipStream_t stream) {
    const float* sk = (const float*)d_in[0];
    const float* im = (const float*)d_in[1];
    float* out = (float*)d_out;
    float* ws = (float*)d_ws;

    unsigned short* skb = (unsigned short*)ws;              // NB*ND bf16 (2 MB)
    unsigned short* imb = skb + (size_t)NB * ND;            // NB*ND bf16 (2 MB)
    float* fbase   = ws + (size_t)NB * ND;
    float* skn     = fbase;                                 // [NB] (c2-scaled)
    float* imn     = fbase + NB;                            // [NB] (c2-scaled)
    float* diag    = fbase + 2 * NB;                        // [NB]
    float* partial = fbase + 3 * NB;                        // [NJB][NB] (512 KB)
    float* gacc    = partial + (size_t)NJB * NB;            // [1]
    unsigned* ticket = (unsigned*)(gacc + 1);               // [1]

    prep_kernel<<<NB / 8, 256, 0, stream>>>(
        sk, im, skb, imb, skn, imn, diag, gacc, ticket);
    dim3 grid(NB / 128, NJB);
    tile_kernel<<<grid, 256, 0, stream>>>(skb, imb, skn, imn, partial);
    finalize_kernel<<<NB / 256, 256, 0, stream>>>(partial, diag, gacc, ticket, out);
}

// Round 9
// 89.173 us; speedup vs baseline: 1.1040x; 1.0197x over previous
//
#include <hip/hip_runtime.h>
#include <math.h>

#define NB 8192
#define ND 128            // bytes per fp8 row
#define GSTEP 64          // j rows staged per step
#define NSTEP 4           // steps per block -> 256 j per block
#define NJB 32            // j-groups (8192 / 256)

// (log2 e)^2 folded into the squared-norm terms: sqrt(c2*sq) = d*log2e,
// v_exp_f32(-that) = exp(-d).
#define C2F 2.0813689810056077f
#define NC2 (-4.1627379620112154f)   // -2*c2, fma coefficient on dot

typedef float f32x4 __attribute__((ext_vector_type(4)));

typedef __attribute__((address_space(3))) void lds_void_t;
typedef __attribute__((address_space(1))) const void gconst_void_t;

__device__ __forceinline__ unsigned f2bf(float f) {
    union { float f; unsigned u; } v; v.f = f;
    unsigned r = v.u + 0x7FFFu + ((v.u >> 16) & 1u);
    return r >> 16;
}

// prep: 2 rows per wave (32 lanes each, float4 loads). Emits fp8 e4m3 copies,
// c2-scaled ||sk||^2 / ||im||^2 (fp32), diag = ||sk-im|| (fp32).
__global__ void __launch_bounds__(256) prep_kernel(
    const float* __restrict__ sk, const float* __restrict__ im,
    unsigned* __restrict__ skb8, unsigned* __restrict__ imb8,
    float* __restrict__ skn, float* __restrict__ imn,
    float* __restrict__ diag, float* __restrict__ gacc,
    unsigned* __restrict__ ticket) {
    if (blockIdx.x == 0 && threadIdx.x == 0) { *gacc = 0.f; *ticket = 0u; }
    const int wave = threadIdx.x >> 6, lane = threadIdx.x & 63;
    const int half = lane >> 5, l32 = lane & 31;
    const int row = blockIdx.x * 8 + wave * 2 + half;
    const size_t off = (size_t)row * 128 + l32 * 4;
    const float4 a = *reinterpret_cast<const float4*>(sk + off);
    const float4 b = *reinterpret_cast<const float4*>(im + off);
    unsigned pa = 0, pb = 0;
    pa = __builtin_amdgcn_cvt_pk_fp8_f32(a.x, a.y, pa, false);
    pa = __builtin_amdgcn_cvt_pk_fp8_f32(a.z, a.w, pa, true);
    pb = __builtin_amdgcn_cvt_pk_fp8_f32(b.x, b.y, pb, false);
    pb = __builtin_amdgcn_cvt_pk_fp8_f32(b.z, b.w, pb, true);
    skb8[row * 32 + l32] = pa;
    imb8[row * 32 + l32] = pb;
    float sa = a.x * a.x + a.y * a.y + a.z * a.z + a.w * a.w;
    float sb = b.x * b.x + b.y * b.y + b.z * b.z + b.w * b.w;
    float dx = a.x - b.x, dy = a.y - b.y, dz = a.z - b.z, dw = a.w - b.w;
    float sd = dx * dx + dy * dy + dz * dz + dw * dw;
#pragma unroll
    for (int st = 1; st < 32; st <<= 1) {
        sa += __shfl_xor(sa, st);
        sb += __shfl_xor(sb, st);
        sd += __shfl_xor(sd, st);
    }
    if (l32 == 0) {
        skn[row] = sa * C2F;
        imn[row] = sb * C2F;
        diag[row] = sqrtf(sd);
    }
}

// tile: block = 256 threads (4 waves), each wave 64j x 32i, fp8 MFMA.
// B (sk) fragments (8 B each) loaded from global ONCE per block into regs.
// A (im) staged per step (8 KB) via global_load_lds, double-buffered;
// source pair-swizzled p ^ ((row>>1)&7); ds_read_b64 slot (kk*4+hi)^(lo&14)
// -> same involution, <=2-way bank conflicts. One barrier per step.
__global__ void __launch_bounds__(256, 5) tile_kernel(
    const unsigned char* __restrict__ skb8, const unsigned char* __restrict__ imb8,
    const float* __restrict__ skn, const float* __restrict__ imn,
    float* __restrict__ partial) {
    __shared__ unsigned char Ast[2][GSTEP * ND];   // 2 x 8 KB

    const int t = threadIdx.x;
    const int w = t >> 6, lane = t & 63;            // w in 0..3
    const int hi = lane >> 4, lo = lane & 15;
    const int iw = blockIdx.x * 128 + w * 32;       // wave's 32 i columns
    const int jg0 = blockIdx.y * (GSTEP * NSTEP);   // block's j base

    // Persistent B (sk) fragments: bfr[n][kk]; col = lo, k = kk*32 + hi*8.
    long bfr[2][4];
#pragma unroll
    for (int n = 0; n < 2; ++n) {
        const unsigned char* bp = skb8 + (size_t)(iw + n * 16 + lo) * ND + hi * 8;
#pragma unroll
        for (int kk = 0; kk < 4; ++kk)
            bfr[n][kk] = *reinterpret_cast<const long*>(bp + kk * 32);
    }
    float skv[2];
#pragma unroll
    for (int n = 0; n < 2; ++n) skv[n] = skn[iw + n * 16 + lo];

    // Stage a 64-row fp8 im step-tile (8 KB = 8 instrs; wave w rows [w*16,w*16+16)).
    // LDS linear dest; global source 16-B pair swizzled by ((row>>1)&7).
#define STAGE_A(buf, jrow0)                                                       \
    {                                                                             \
        _Pragma("unroll")                                                         \
        for (int q = 0; q < 2; ++q) {                                             \
            const int rl = w * 16 + q * 8 + (lane >> 3);                          \
            const int sp = (lane & 7) ^ ((rl >> 1) & 7);                          \
            const unsigned char* gp = imb8 + (size_t)((jrow0) + rl) * ND + sp * 16;\
            __builtin_amdgcn_global_load_lds((gconst_void_t*)gp,                  \
                (lds_void_t*)(&Ast[(buf)][(w * 16 + q * 8) * ND]), 16, 0, 0);     \
        }                                                                         \
    }

    STAGE_A(0, jg0)
    __syncthreads();

    float sacc[2] = {0.f, 0.f};

    for (int s = 0; s < NSTEP; ++s) {
        const int jb = jg0 + s * GSTEP;
        if (s + 1 < NSTEP) STAGE_A((s + 1) & 1, jb + GSTEP)

        // c2-scaled im norms for this step's j rows (j = jb + m*16 + hi*4 + r).
        float imnv[4][4];
#pragma unroll
        for (int m = 0; m < 4; ++m) {
            float4 v = *reinterpret_cast<const float4*>(imn + jb + m * 16 + hi * 4);
            imnv[m][0] = v.x; imnv[m][1] = v.y; imnv[m][2] = v.z; imnv[m][3] = v.w;
        }

        f32x4 acc[4][2];
#pragma unroll
        for (int m = 0; m < 4; ++m)
#pragma unroll
            for (int n = 0; n < 2; ++n)
                acc[m][n] = (f32x4){0.f, 0.f, 0.f, 0.f};

        const char* Ab = (const char*)Ast[s & 1];
#pragma unroll
        for (int kk = 0; kk < 4; ++kk) {
            long af[4];
#pragma unroll
            for (int m = 0; m < 4; ++m)
                af[m] = *reinterpret_cast<const long*>(
                    Ab + (m * 16 + lo) * ND + (((kk * 4 + hi) ^ (lo & 14)) << 3));
#pragma unroll
            for (int m = 0; m < 4; ++m)
#pragma unroll
                for (int n = 0; n < 2; ++n)
                    acc[m][n] = __builtin_amdgcn_mfma_f32_16x16x32_fp8_fp8(
                        af[m], bfr[n][kk], acc[m][n], 0, 0, 0);
        }

        // Epilogue: i fixed per n (col=lo); j = jb + m*16 + hi*4 + r.
        // sq2 may be ~-eps at d~0: sqrt(abs()) via free input modifier.
#pragma unroll
        for (int n = 0; n < 2; ++n) {
            float ssum = 0.f;
#pragma unroll
            for (int m = 0; m < 4; ++m) {
#pragma unroll
                for (int r = 0; r < 4; ++r) {
                    float sq2 = fmaf(NC2, acc[m][n][r], skv[n]) + imnv[m][r];
                    float d2;
                    asm("v_sqrt_f32 %0, abs(%1)" : "=v"(d2) : "v"(sq2));
                    float e;
                    asm("v_exp_f32 %0, -%1" : "=v"(e) : "v"(d2));
                    ssum += e;
                }
            }
            sacc[n] += ssum;
        }
        __syncthreads();   // drains this step's prefetch vmcnt; buffer swap safe
    }

    // Fold the hi groups (j-partitions) and write this wave's 32 partials.
#pragma unroll
    for (int n = 0; n < 2; ++n) {
        sacc[n] += __shfl_xor(sacc[n], 16);
        sacc[n] += __shfl_xor(sacc[n], 32);
    }
    if (lane < 16) {
        partial[(size_t)blockIdx.y * NB + iw + lo] = sacc[0];
        partial[(size_t)blockIdx.y * NB + iw + 16 + lo] = sacc[1];
    }
#undef STAGE_A
}

// finalize: thread per row; 32 coalesced partial loads; log + diag; block
// reduce; device atomic + ticket, last block writes the mean.
__global__ void finalize_kernel(const float* __restrict__ partial,
                                const float* __restrict__ diag,
                                float* __restrict__ gacc, unsigned* __restrict__ ticket,
                                float* __restrict__ out) {
    const int i = blockIdx.x * 256 + threadIdx.x;
    float rs = 0.f;
#pragma unroll
    for (int c = 0; c < NJB; ++c) rs += partial[(size_t)c * NB + i];
    float v = __logf(rs) + diag[i];
    __shared__ float red[256];
    red[threadIdx.x] = v;
    __syncthreads();
    for (int st = 128; st > 0; st >>= 1) {
        if (threadIdx.x < st) red[threadIdx.x] += red[threadIdx.x + st];
        __syncthreads();
    }
    if (threadIdx.x == 0) {
        atomicAdd(gacc, red[0]);
        __threadfence();
        unsigned old = atomicAdd(ticket, 1u);
        if (old == (NB / 256) - 1) {
            float tot = atomicAdd(gacc, 0.f);   // device-coherent read
            out[0] = tot / (float)NB;
        }
    }
}

extern "C" void kernel_launch(void* const* d_in, const int* in_sizes, int n_in,
                              void* d_out, int out_size, void* d_ws, size_t ws_size,
                              hipStream_t stream) {
    const float* sk = (const float*)d_in[0];
    const float* im = (const float*)d_in[1];
    float* out = (float*)d_out;
    float* ws = (float*)d_ws;

    unsigned char* skb8 = (unsigned char*)ws;               // NB*128 fp8 (1 MB)
    unsigned char* imb8 = skb8 + (size_t)NB * ND;           // NB*128 fp8 (1 MB)
    float* fbase   = ws + (size_t)NB * ND / 2;              // 2 MB consumed above
    float* skn     = fbase;                                 // [NB] (c2-scaled)
    float* imn     = fbase + NB;                            // [NB] (c2-scaled)
    float* diag    = fbase + 2 * NB;                        // [NB]
    float* partial = fbase + 3 * NB;                        // [NJB][NB] (1 MB)
    float* gacc    = partial + (size_t)NJB * NB;            // [1]
    unsigned* ticket = (unsigned*)(gacc + 1);               // [1]

    prep_kernel<<<NB / 8, 256, 0, stream>>>(
        sk, im, (unsigned*)skb8, (unsigned*)imb8, skn, imn, diag, gacc, ticket);
    dim3 grid(NB / 128, NJB);
    tile_kernel<<<grid, 256, 0, stream>>>(skb8, imb8, skn, imn, partial);
    finalize_kernel<<<NB / 256, 256, 0, stream>>>(partial, diag, gacc, ticket, out);
}

// Round 10
// 87.513 us; speedup vs baseline: 1.1249x; 1.0190x over previous
//
#include <hip/hip_runtime.h>
#include <math.h>

#define NB 8192
#define ND 128            // elements (bytes in fp8) per row
#define GSTEP 64          // j rows per step
#define NSTEP 8           // steps per wave -> 512 j per wave
#define NJB 16            // j-groups (8192 / 512)

// (log2 e)^2 folded into the squared-norm terms: sqrt(c2*sq) = d*log2e,
// v_exp_f32(-that) = exp(-d).
#define C2F 2.0813689810056077f
#define NC2 (-4.1627379620112154f)   // -2*c2, fma coefficient on dot

typedef float f32x4 __attribute__((ext_vector_type(4)));
typedef unsigned long long ull;

// prep: 16 threads per row, each owns one 8-byte fp8 chunk (k = j*8..j*8+8).
// Emits fp8 e4m3 in MFMA FRAGMENT-MAJOR layout (8-B units):
//   idx = (row>>4)*256 + kk*64 + hi*16 + (row&15),  kk=j>>2, hi=j&3
// so a wave's fragment load in tile is one coalesced 512-B global load.
// Also: c2-scaled ||sk||^2 / ||im||^2 (fp32), diag = ||sk-im|| (fp32).
__global__ void __launch_bounds__(256) prep_kernel(
    const float* __restrict__ sk, const float* __restrict__ im,
    ull* __restrict__ skf, ull* __restrict__ imf,
    float* __restrict__ skn, float* __restrict__ imn,
    float* __restrict__ diag, float* __restrict__ gacc,
    unsigned* __restrict__ ticket) {
    if (blockIdx.x == 0 && threadIdx.x == 0) { *gacc = 0.f; *ticket = 0u; }
    const int gtid = blockIdx.x * 256 + threadIdx.x;
    const int row = gtid >> 4;          // 0..8191
    const int j = gtid & 15;            // 8-B chunk index
    const size_t off = (size_t)row * ND + j * 8;
    const float4* a4 = reinterpret_cast<const float4*>(sk + off);
    const float4* b4 = reinterpret_cast<const float4*>(im + off);
    float4 a0 = a4[0], a1 = a4[1], b0 = b4[0], b1 = b4[1];

    unsigned al = 0, ah = 0, bl = 0, bh = 0;
    al = __builtin_amdgcn_cvt_pk_fp8_f32(a0.x, a0.y, al, false);
    al = __builtin_amdgcn_cvt_pk_fp8_f32(a0.z, a0.w, al, true);
    ah = __builtin_amdgcn_cvt_pk_fp8_f32(a1.x, a1.y, ah, false);
    ah = __builtin_amdgcn_cvt_pk_fp8_f32(a1.z, a1.w, ah, true);
    bl = __builtin_amdgcn_cvt_pk_fp8_f32(b0.x, b0.y, bl, false);
    bl = __builtin_amdgcn_cvt_pk_fp8_f32(b0.z, b0.w, bl, true);
    bh = __builtin_amdgcn_cvt_pk_fp8_f32(b1.x, b1.y, bh, false);
    bh = __builtin_amdgcn_cvt_pk_fp8_f32(b1.z, b1.w, bh, true);

    const size_t didx = (size_t)(row >> 4) * 256 + (j >> 2) * 64 + (j & 3) * 16 + (row & 15);
    skf[didx] = (ull)al | ((ull)ah << 32);
    imf[didx] = (ull)bl | ((ull)bh << 32);

    float sa = a0.x*a0.x + a0.y*a0.y + a0.z*a0.z + a0.w*a0.w
             + a1.x*a1.x + a1.y*a1.y + a1.z*a1.z + a1.w*a1.w;
    float sb = b0.x*b0.x + b0.y*b0.y + b0.z*b0.z + b0.w*b0.w
             + b1.x*b1.x + b1.y*b1.y + b1.z*b1.z + b1.w*b1.w;
    float d0 = a0.x-b0.x, d1 = a0.y-b0.y, d2 = a0.z-b0.z, d3 = a0.w-b0.w;
    float d4 = a1.x-b1.x, d5 = a1.y-b1.y, d6 = a1.z-b1.z, d7 = a1.w-b1.w;
    float sd = d0*d0 + d1*d1 + d2*d2 + d3*d3 + d4*d4 + d5*d5 + d6*d6 + d7*d7;
#pragma unroll
    for (int st = 1; st < 16; st <<= 1) {   // 16-lane groups = one row
        sa += __shfl_xor(sa, st);
        sb += __shfl_xor(sb, st);
        sd += __shfl_xor(sd, st);
    }
    if (j == 0) {
        skn[row] = sa * C2F;
        imn[row] = sb * C2F;
        diag[row] = sqrtf(sd);
    }
}

// tile: barrier-free, LDS-free. Each wave owns 32 i-cols x 512 j-rows
// (8 steps of 64 j). All MFMA fragments read DIRECTLY from the
// fragment-major fp8 arrays with fully-coalesced 8 B/lane loads
// (everything is L2-resident: im 1 MB, sk 1 MB). Waves run at their own
// phase -> VALU (the floor: 64M sqrt + 64M exp) stays fed by TLP.
__global__ void __launch_bounds__(256, 4) tile_kernel(
    const ull* __restrict__ skf, const ull* __restrict__ imf,
    const float* __restrict__ skn, const float* __restrict__ imn,
    float* __restrict__ partial) {
    const int w = threadIdx.x >> 6, lane = threadIdx.x & 63;
    const int hi = lane >> 4, lo = lane & 15;
    const int gw = blockIdx.x * 4 + w;       // 0..4095
    const int iw = (gw & 255) * 32;          // wave's 32 i columns
    const int jgrp = gw >> 8;                // 0..15
    const int jg0 = jgrp * (GSTEP * NSTEP);  // wave's j base

    // Persistent B (sk) fragments + c2-scaled sk norms.
    long bfr[2][4];
    const int gi = iw >> 4;
#pragma unroll
    for (int n = 0; n < 2; ++n)
#pragma unroll
        for (int kk = 0; kk < 4; ++kk)
            bfr[n][kk] = (long)skf[(size_t)(gi + n) * 256 + kk * 64 + lane];
    float skv[2];
#pragma unroll
    for (int n = 0; n < 2; ++n) skv[n] = skn[iw + n * 16 + lo];

    float sacc[2] = {0.f, 0.f};

    for (int s = 0; s < NSTEP; ++s) {
        const int jb = jg0 + s * GSTEP;
        const size_t ga = (size_t)(jb >> 4) * 256;

        // c2-scaled im norms for this step (j = jb + m*16 + hi*4 + r).
        float imnv[4][4];
#pragma unroll
        for (int m = 0; m < 4; ++m) {
            float4 v = *reinterpret_cast<const float4*>(imn + jb + m * 16 + hi * 4);
            imnv[m][0] = v.x; imnv[m][1] = v.y; imnv[m][2] = v.z; imnv[m][3] = v.w;
        }

        f32x4 acc[4][2];
#pragma unroll
        for (int m = 0; m < 4; ++m)
#pragma unroll
            for (int n = 0; n < 2; ++n)
                acc[m][n] = (f32x4){0.f, 0.f, 0.f, 0.f};

#pragma unroll
        for (int kk = 0; kk < 4; ++kk) {
            long af[4];
#pragma unroll
            for (int m = 0; m < 4; ++m)
                af[m] = (long)imf[ga + (size_t)m * 256 + kk * 64 + lane];
#pragma unroll
            for (int m = 0; m < 4; ++m)
#pragma unroll
                for (int n = 0; n < 2; ++n)
                    acc[m][n] = __builtin_amdgcn_mfma_f32_16x16x32_fp8_fp8(
                        af[m], bfr[n][kk], acc[m][n], 0, 0, 0);
        }

        // Epilogue: i fixed per n (col = lo); j = jb + m*16 + hi*4 + r.
#pragma unroll
        for (int n = 0; n < 2; ++n) {
            float ssum = 0.f;
#pragma unroll
            for (int m = 0; m < 4; ++m) {
#pragma unroll
                for (int r = 0; r < 4; ++r) {
                    float sq2 = fmaf(NC2, acc[m][n][r], skv[n]) + imnv[m][r];
                    float d2;
                    asm("v_sqrt_f32 %0, abs(%1)" : "=v"(d2) : "v"(sq2));
                    float e;
                    asm("v_exp_f32 %0, -%1" : "=v"(e) : "v"(d2));
                    ssum += e;
                }
            }
            sacc[n] += ssum;
        }
    }

    // Fold the hi groups (j-partitions); write this wave's 32 partials.
#pragma unroll
    for (int n = 0; n < 2; ++n) {
        sacc[n] += __shfl_xor(sacc[n], 16);
        sacc[n] += __shfl_xor(sacc[n], 32);
    }
    if (lane < 16) {
        partial[(size_t)jgrp * NB + iw + lo] = sacc[0];
        partial[(size_t)jgrp * NB + iw + 16 + lo] = sacc[1];
    }
}

// finalize: thread per row; 16 coalesced partial loads; log + diag; block
// reduce; device atomic + ticket, last block writes the mean.
__global__ void finalize_kernel(const float* __restrict__ partial,
                                const float* __restrict__ diag,
                                float* __restrict__ gacc, unsigned* __restrict__ ticket,
                                float* __restrict__ out) {
    const int i = blockIdx.x * 256 + threadIdx.x;
    float rs = 0.f;
#pragma unroll
    for (int c = 0; c < NJB; ++c) rs += partial[(size_t)c * NB + i];
    float v = __logf(rs) + diag[i];
    __shared__ float red[256];
    red[threadIdx.x] = v;
    __syncthreads();
    for (int st = 128; st > 0; st >>= 1) {
        if (threadIdx.x < st) red[threadIdx.x] += red[threadIdx.x + st];
        __syncthreads();
    }
    if (threadIdx.x == 0) {
        atomicAdd(gacc, red[0]);
        __threadfence();
        unsigned old = atomicAdd(ticket, 1u);
        if (old == (NB / 256) - 1) {
            float tot = atomicAdd(gacc, 0.f);   // device-coherent read
            out[0] = tot / (float)NB;
        }
    }
}

extern "C" void kernel_launch(void* const* d_in, const int* in_sizes, int n_in,
                              void* d_out, int out_size, void* d_ws, size_t ws_size,
                              hipStream_t stream) {
    const float* sk = (const float*)d_in[0];
    const float* im = (const float*)d_in[1];
    float* out = (float*)d_out;
    float* ws = (float*)d_ws;

    ull* skf = (ull*)ws;                                    // NB*128 fp8, frag-major (1 MB)
    ull* imf = skf + (size_t)NB * ND / 8;                   // (1 MB)
    float* fbase   = ws + (size_t)NB * ND / 2;              // 2 MB consumed above
    float* skn     = fbase;                                 // [NB] (c2-scaled)
    float* imn     = fbase + NB;                            // [NB] (c2-scaled)
    float* diag    = fbase + 2 * NB;                        // [NB]
    float* partial = fbase + 3 * NB;                        // [NJB][NB] (512 KB)
    float* gacc    = partial + (size_t)NJB * NB;            // [1]
    unsigned* ticket = (unsigned*)(gacc + 1);               // [1]

    prep_kernel<<<NB * 16 / 256, 256, 0, stream>>>(
        sk, im, skf, imf, skn, imn, diag, gacc, ticket);
    tile_kernel<<<1024, 256, 0, stream>>>(skf, imf, skn, imn, partial);
    finalize_kernel<<<NB / 256, 256, 0, stream>>>(partial, diag, gacc, ticket, out);
}